// Round 1
// baseline (312.037 us; speedup 1.0000x reference)
//
#include <hip/hip_runtime.h>
#include <hip/hip_bf16.h>

typedef __attribute__((ext_vector_type(8))) short short8;
typedef __attribute__((ext_vector_type(4))) float float4v;

#define N_NODES 131072
#define E_EDGES 256
#define IN_CH   128
#define OUT_CH  256

// ---------------------------------------------------------------------------
// k1: build per-node 256-bit incidence masks + gram nonzero-pattern bitmatrix.
// gram_nz[e',e] = 1 iff edges e' and e share a node = OR_n mask_n ⊗ mask_n.
// One wave per node: 4 coalesced 256B loads + 4 ballots. LDS-accumulate the
// 8 KiB bitmatrix per block, one pass of global atomicOr at the end.
// ---------------------------------------------------------------------------
__global__ __launch_bounds__(256) void k_gram(const float* __restrict__ H,
                                              unsigned long long* __restrict__ masks,
                                              unsigned* __restrict__ gram) {
  __shared__ unsigned gsh[E_EDGES * 8];
  for (int i = threadIdx.x; i < E_EDGES * 8; i += 256) gsh[i] = 0u;
  __syncthreads();

  const int wave = threadIdx.x >> 6;
  const int lane = threadIdx.x & 63;
  const int base = (blockIdx.x * 4 + wave) * 64;  // 64 nodes per wave

  auto upd = [&](int n, unsigned long long b0, unsigned long long b1,
                 unsigned long long b2, unsigned long long b3) {
    if (lane < 4) {
      unsigned long long v = (lane == 0) ? b0 : (lane == 1) ? b1 : (lane == 2) ? b2 : b3;
      masks[(size_t)n * 4 + lane] = v;
    }
    const unsigned w0 = (unsigned)b0, w1 = (unsigned)(b0 >> 32);
    const unsigned w2 = (unsigned)b1, w3 = (unsigned)(b1 >> 32);
    const unsigned w4 = (unsigned)b2, w5 = (unsigned)(b2 >> 32);
    const unsigned w6 = (unsigned)b3, w7 = (unsigned)(b3 >> 32);
#define GUPD(g, bg)                                                  \
    if ((bg >> lane) & 1ull) {                                       \
      unsigned* gr = &gsh[((g) * 64 + lane) * 8];                    \
      atomicOr(gr + 0, w0); atomicOr(gr + 1, w1);                    \
      atomicOr(gr + 2, w2); atomicOr(gr + 3, w3);                    \
      atomicOr(gr + 4, w4); atomicOr(gr + 5, w5);                    \
      atomicOr(gr + 6, w6); atomicOr(gr + 7, w7);                    \
    }
    GUPD(0, b0) GUPD(1, b1) GUPD(2, b2) GUPD(3, b3)
#undef GUPD
  };

  for (int it = 0; it < 32; ++it) {   // 2 nodes per iter for more loads in flight
    const int n0 = base + it * 2, n1 = n0 + 1;
    const float* r0 = H + (size_t)n0 * E_EDGES;
    const float* r1 = H + (size_t)n1 * E_EDGES;
    float a0 = r0[lane], a1 = r0[lane + 64], a2 = r0[lane + 128], a3 = r0[lane + 192];
    float c0 = r1[lane], c1 = r1[lane + 64], c2 = r1[lane + 128], c3 = r1[lane + 192];
    unsigned long long b0 = __ballot(a0 >= 0.5f);
    unsigned long long b1 = __ballot(a1 >= 0.5f);
    unsigned long long b2 = __ballot(a2 >= 0.5f);
    unsigned long long b3 = __ballot(a3 >= 0.5f);
    upd(n0, b0, b1, b2, b3);
    unsigned long long d0 = __ballot(c0 >= 0.5f);
    unsigned long long d1 = __ballot(c1 >= 0.5f);
    unsigned long long d2 = __ballot(c2 >= 0.5f);
    unsigned long long d3 = __ballot(c3 >= 0.5f);
    upd(n1, d0, d1, d2, d3);
  }
  __syncthreads();
  for (int i = threadIdx.x; i < E_EDGES * 8; i += 256) {
    unsigned v = gsh[i];
    if (v) atomicOr(&gram[i], v);
  }
}

// ---------------------------------------------------------------------------
// k2: per node, dv = popcount(mask) + popcount(OR of selected gram rows);
// s[n] = 1 + 1/sqrt(dv) (0-degree -> 1). Gram bitmatrix cached in LDS.
// ---------------------------------------------------------------------------
__global__ __launch_bounds__(256) void k_scale(const unsigned long long* __restrict__ masks,
                                               const unsigned* __restrict__ gram,
                                               float* __restrict__ s) {
  __shared__ unsigned gsh[E_EDGES * 8];
  for (int i = threadIdx.x; i < E_EDGES * 8; i += 256) gsh[i] = gram[i];
  __syncthreads();
  const int n = blockIdx.x * 256 + threadIdx.x;
  const unsigned long long m0 = masks[(size_t)n * 4 + 0];
  const unsigned long long m1 = masks[(size_t)n * 4 + 1];
  const unsigned long long m2 = masks[(size_t)n * 4 + 2];
  const unsigned long long m3 = masks[(size_t)n * 4 + 3];
  int dv = __popcll(m0) + __popcll(m1) + __popcll(m2) + __popcll(m3);
  unsigned o0 = 0, o1 = 0, o2 = 0, o3 = 0, o4 = 0, o5 = 0, o6 = 0, o7 = 0;
  auto scan = [&](unsigned long long bits, int g) {
    while (bits) {
      int t = __builtin_ctzll(bits);
      bits &= bits - 1;
      const unsigned* gr = &gsh[((g << 6) + t) * 8];
      o0 |= gr[0]; o1 |= gr[1]; o2 |= gr[2]; o3 |= gr[3];
      o4 |= gr[4]; o5 |= gr[5]; o6 |= gr[6]; o7 |= gr[7];
    }
  };
  scan(m0, 0); scan(m1, 1); scan(m2, 2); scan(m3, 3);
  dv += __popc(o0) + __popc(o1) + __popc(o2) + __popc(o3) +
        __popc(o4) + __popc(o5) + __popc(o6) + __popc(o7);
  float sv = 1.0f;
  if (dv > 0) sv += 1.0f / sqrtf((float)dv);
  s[n] = sv;
}

// ---------------------------------------------------------------------------
// convW: W fp32 [128][256] -> bf16 in MFMA B-fragment order.
// frag (nt, ks): lane holds B[k = ks*32 + (lane>>4)*8 + j][n = nt*16 + (lane&15)]
// stored contiguously: Wb[((nt*4+ks)*64 + lane)*8 + j]  -> 16B/lane loads in GEMM.
// ---------------------------------------------------------------------------
__global__ __launch_bounds__(64) void k_convw(const float* __restrict__ W,
                                              __hip_bfloat16* __restrict__ Wb) {
  const int b = blockIdx.x;        // 0..63 : nt = b>>2, ks = b&3
  const int lane = threadIdx.x;    // 0..63
  const int nt = b >> 2, ks = b & 3;
  const int col = nt * 16 + (lane & 15);
  const int kbase = ks * 32 + (lane >> 4) * 8;
#pragma unroll
  for (int j = 0; j < 8; ++j)
    Wb[((size_t)(b * 64 + lane)) * 8 + j] = __float2bfloat16(W[(kbase + j) * OUT_CH + col]);
}

// ---------------------------------------------------------------------------
// k3: out[n,c] = s[n] * (U[n,:] @ W[:,c]) + bias[c], bf16 MFMA 16x16x32.
// Block: 256 thr (4 waves), tile 64 rows x 256 cols, full K=128 staged in LDS.
// A LDS row stride 136 (pad +8 bf16) to break 16-way bank conflicts on
// ds_read_b128 fragment loads while keeping 16B alignment.
// ---------------------------------------------------------------------------
__global__ __launch_bounds__(256) void k_gemm(const float* __restrict__ U,
                                              const __hip_bfloat16* __restrict__ Wb,
                                              const float* __restrict__ s,
                                              const float* __restrict__ bias,
                                              float* __restrict__ out) {
  __shared__ __hip_bfloat16 A[64 * 136];
  __shared__ float ssh[64];
  __shared__ float bsh[OUT_CH];

  const int tid = threadIdx.x;
  const int blockRow = blockIdx.x * 64;

  // stage U tile (64 x 128 fp32) -> bf16 LDS, coalesced float4
#pragma unroll
  for (int i = tid; i < 64 * 32; i += 256) {
    const int row = i >> 5, c4 = i & 31;
    float4 v = reinterpret_cast<const float4*>(U + (size_t)(blockRow + row) * IN_CH)[c4];
    __hip_bfloat16* dst = &A[row * 136 + c4 * 4];
    dst[0] = __float2bfloat16(v.x);
    dst[1] = __float2bfloat16(v.y);
    dst[2] = __float2bfloat16(v.z);
    dst[3] = __float2bfloat16(v.w);
  }
  if (tid < 64) ssh[tid] = s[blockRow + tid];
  bsh[tid] = bias[tid];
  __syncthreads();

  const int wave = tid >> 6, lane = tid & 63;
  const int quad = lane >> 4, c16 = lane & 15;

  float4v acc[4][4];
#pragma unroll
  for (int m = 0; m < 4; ++m)
#pragma unroll
    for (int nn = 0; nn < 4; ++nn)
      acc[m][nn] = (float4v){0.f, 0.f, 0.f, 0.f};

#pragma unroll
  for (int ks = 0; ks < 4; ++ks) {
    short8 a[4], b[4];
#pragma unroll
    for (int m = 0; m < 4; ++m)
      a[m] = *reinterpret_cast<const short8*>(&A[(m * 16 + c16) * 136 + ks * 32 + quad * 8]);
#pragma unroll
    for (int nn = 0; nn < 4; ++nn)
      b[nn] = *reinterpret_cast<const short8*>(
          Wb + ((size_t)(((wave * 4 + nn) * 4 + ks) * 64 + lane)) * 8);
#pragma unroll
    for (int m = 0; m < 4; ++m)
#pragma unroll
      for (int nn = 0; nn < 4; ++nn)
        acc[m][nn] = __builtin_amdgcn_mfma_f32_16x16x32_bf16(a[m], b[nn], acc[m][nn], 0, 0, 0);
  }

  // epilogue: C/D layout col = lane&15, row = quad*4 + reg
#pragma unroll
  for (int m = 0; m < 4; ++m) {
#pragma unroll
    for (int nn = 0; nn < 4; ++nn) {
      const int col = wave * 64 + nn * 16 + c16;
      const float bv = bsh[col];
#pragma unroll
      for (int r = 0; r < 4; ++r) {
        const int row = m * 16 + quad * 4 + r;
        out[(size_t)(blockRow + row) * OUT_CH + col] = ssh[row] * acc[m][nn][r] + bv;
      }
    }
  }
}

// ---------------------------------------------------------------------------
extern "C" void kernel_launch(void* const* d_in, const int* in_sizes, int n_in,
                              void* d_out, int out_size, void* d_ws, size_t ws_size,
                              hipStream_t stream) {
  const float* H    = (const float*)d_in[0];
  const float* U    = (const float*)d_in[1];
  const float* W    = (const float*)d_in[2];
  const float* bias = (const float*)d_in[3];
  float* out = (float*)d_out;

  // ws layout: gram bitmatrix (8 KiB) | s (512 KiB) | Wb (64 KiB)
  char* ws = (char*)d_ws;
  unsigned* gram = (unsigned*)ws;
  float* s = (float*)(ws + 8192);
  __hip_bfloat16* Wb = (__hip_bfloat16*)(ws + 8192 + 524288);

  // node masks live in d_out's first 4 MiB: dead scratch until k_gemm
  // overwrites all of d_out (masks fully consumed by k_scale before that).
  unsigned long long* masks = (unsigned long long*)d_out;

  hipMemsetAsync(gram, 0, E_EDGES * 8 * sizeof(unsigned), stream);
  k_gram<<<dim3(512), dim3(256), 0, stream>>>(H, masks, gram);
  k_convw<<<dim3(64), dim3(64), 0, stream>>>(W, Wb);
  k_scale<<<dim3(512), dim3(256), 0, stream>>>(masks, gram, s);
  k_gemm<<<dim3(N_NODES / 64), dim3(256), 0, stream>>>(U, Wb, s, bias, out);
}

// Round 2
// 302.987 us; speedup vs baseline: 1.0299x; 1.0299x over previous
//
#include <hip/hip_runtime.h>
#include <hip/hip_bf16.h>

typedef __attribute__((ext_vector_type(8))) short short8;
typedef __attribute__((ext_vector_type(4))) float float4v;

#define N_NODES 131072
#define E_EDGES 256
#define IN_CH   128
#define OUT_CH  256

// ---------------------------------------------------------------------------
// k1: per-node 256-bit incidence masks + gram nonzero-pattern bitmatrix.
// gram_nz[e',e] = 1 iff edges e',e share a node = OR_n mask_n ⊗ mask_n.
// Lane L of each wave owns gram rows {L, 64+L, 128+L, 192+L} in 32 VGPRs:
// update per node is pure predicated VALU (no LDS atomics in the loop).
// One-time LDS merge + conditional global atomicOr at the end.
// ---------------------------------------------------------------------------
__global__ __launch_bounds__(512) void k_gram(const float* __restrict__ H,
                                              unsigned long long* __restrict__ masks,
                                              unsigned* __restrict__ gram) {
  const int wave = threadIdx.x >> 6;   // 0..7
  const int lane = threadIdx.x & 63;
  const int base = (blockIdx.x * 8 + wave) * 64;  // 64 nodes per wave

  unsigned r[4][8];
#pragma unroll
  for (int g = 0; g < 4; ++g)
#pragma unroll
    for (int j = 0; j < 8; ++j) r[g][j] = 0u;

  for (int it = 0; it < 16; ++it) {    // 4 nodes/iter -> 16 loads in flight
    const int n0 = base + it * 4;
    float v[4][4];
#pragma unroll
    for (int q = 0; q < 4; ++q) {
      const float* row = H + (size_t)(n0 + q) * E_EDGES;
#pragma unroll
      for (int g = 0; g < 4; ++g) v[q][g] = row[lane + g * 64];
    }
#pragma unroll
    for (int q = 0; q < 4; ++q) {
      unsigned long long b0 = __ballot(v[q][0] >= 0.5f);
      unsigned long long b1 = __ballot(v[q][1] >= 0.5f);
      unsigned long long b2 = __ballot(v[q][2] >= 0.5f);
      unsigned long long b3 = __ballot(v[q][3] >= 0.5f);
      if (lane < 4)
        masks[(size_t)(n0 + q) * 4 + lane] =
            (lane == 0) ? b0 : (lane == 1) ? b1 : (lane == 2) ? b2 : b3;
      unsigned w[8] = {(unsigned)b0, (unsigned)(b0 >> 32),
                       (unsigned)b1, (unsigned)(b1 >> 32),
                       (unsigned)b2, (unsigned)(b2 >> 32),
                       (unsigned)b3, (unsigned)(b3 >> 32)};
      const unsigned long long bb[4] = {b0, b1, b2, b3};
#pragma unroll
      for (int g = 0; g < 4; ++g) {
        const unsigned sel = ((unsigned)(bb[g] >> lane) & 1u) ? 0xFFFFFFFFu : 0u;
#pragma unroll
        for (int j = 0; j < 8; ++j) r[g][j] |= w[j] & sel;
      }
    }
  }

  __shared__ unsigned gsh[E_EDGES * 8];
  for (int i = threadIdx.x; i < E_EDGES * 8; i += 512) gsh[i] = 0u;
  __syncthreads();
#pragma unroll
  for (int g = 0; g < 4; ++g)
#pragma unroll
    for (int j = 0; j < 8; ++j)
      if (r[g][j]) atomicOr(&gsh[(g * 64 + lane) * 8 + j], r[g][j]);
  __syncthreads();
  for (int i = threadIdx.x; i < E_EDGES * 8; i += 512) {
    unsigned v = gsh[i];
    if (v) {
      // racy pre-read is safe: OR is monotone, stale read only costs an atomic
      unsigned old = gram[i];
      if ((old | v) != old) atomicOr(&gram[i], v);
    }
  }
}

// ---------------------------------------------------------------------------
// k2: dv = popcount(mask) + popcount(OR of selected gram rows);
// s[n] = 1 + 1/sqrt(dv) (0-degree -> 1). Gram rows in LDS padded to stride 9
// (odd stride -> gather hits all 32 banks instead of 4).
// ---------------------------------------------------------------------------
__global__ __launch_bounds__(256) void k_scale(const unsigned long long* __restrict__ masks,
                                               const unsigned* __restrict__ gram,
                                               float* __restrict__ s) {
  __shared__ unsigned gsh[E_EDGES * 9];
  for (int i = threadIdx.x; i < E_EDGES * 8; i += 256)
    gsh[(i >> 3) * 9 + (i & 7)] = gram[i];
  __syncthreads();
  const int n = blockIdx.x * 256 + threadIdx.x;
  const unsigned long long m0 = masks[(size_t)n * 4 + 0];
  const unsigned long long m1 = masks[(size_t)n * 4 + 1];
  const unsigned long long m2 = masks[(size_t)n * 4 + 2];
  const unsigned long long m3 = masks[(size_t)n * 4 + 3];
  int dv = __popcll(m0) + __popcll(m1) + __popcll(m2) + __popcll(m3);
  unsigned o0 = 0, o1 = 0, o2 = 0, o3 = 0, o4 = 0, o5 = 0, o6 = 0, o7 = 0;
  auto scan = [&](unsigned long long bits, int g) {
    while (bits) {
      int t = __builtin_ctzll(bits);
      bits &= bits - 1;
      const unsigned* gr = &gsh[((g << 6) + t) * 9];
      o0 |= gr[0]; o1 |= gr[1]; o2 |= gr[2]; o3 |= gr[3];
      o4 |= gr[4]; o5 |= gr[5]; o6 |= gr[6]; o7 |= gr[7];
    }
  };
  scan(m0, 0); scan(m1, 1); scan(m2, 2); scan(m3, 3);
  dv += __popc(o0) + __popc(o1) + __popc(o2) + __popc(o3) +
        __popc(o4) + __popc(o5) + __popc(o6) + __popc(o7);
  float sv = 1.0f;
  if (dv > 0) sv += 1.0f / sqrtf((float)dv);
  s[n] = sv;
}

// ---------------------------------------------------------------------------
// convW: W fp32 [128][256] -> bf16 in MFMA B-fragment order.
// frag (nt, ks): lane holds B[k = ks*32 + (lane>>4)*8 + j][n = nt*16 + (lane&15)]
// stored contiguously: Wb[((nt*4+ks)*64 + lane)*8 + j]  -> 16B/lane loads in GEMM.
// ---------------------------------------------------------------------------
__global__ __launch_bounds__(64) void k_convw(const float* __restrict__ W,
                                              __hip_bfloat16* __restrict__ Wb) {
  const int b = blockIdx.x;        // 0..63 : nt = b>>2, ks = b&3
  const int lane = threadIdx.x;    // 0..63
  const int nt = b >> 2, ks = b & 3;
  const int col = nt * 16 + (lane & 15);
  const int kbase = ks * 32 + (lane >> 4) * 8;
#pragma unroll
  for (int j = 0; j < 8; ++j)
    Wb[((size_t)(b * 64 + lane)) * 8 + j] = __float2bfloat16(W[(kbase + j) * OUT_CH + col]);
}

// ---------------------------------------------------------------------------
// k3: out[n,c] = s[n] * (U[n,:] @ W[:,c]) + bias[c], bf16 MFMA 16x16x32.
// Block: 256 thr (4 waves), tile 64 rows x 256 cols, full K=128 staged in LDS.
// A LDS row stride 136 (pad +8 bf16) to break bank conflicts on ds_read_b128.
// ---------------------------------------------------------------------------
__global__ __launch_bounds__(256) void k_gemm(const float* __restrict__ U,
                                              const __hip_bfloat16* __restrict__ Wb,
                                              const float* __restrict__ s,
                                              const float* __restrict__ bias,
                                              float* __restrict__ out) {
  __shared__ __hip_bfloat16 A[64 * 136];
  __shared__ float ssh[64];
  __shared__ float bsh[OUT_CH];

  const int tid = threadIdx.x;
  const int blockRow = blockIdx.x * 64;

#pragma unroll
  for (int i = tid; i < 64 * 32; i += 256) {
    const int row = i >> 5, c4 = i & 31;
    float4 v = reinterpret_cast<const float4*>(U + (size_t)(blockRow + row) * IN_CH)[c4];
    __hip_bfloat16* dst = &A[row * 136 + c4 * 4];
    dst[0] = __float2bfloat16(v.x);
    dst[1] = __float2bfloat16(v.y);
    dst[2] = __float2bfloat16(v.z);
    dst[3] = __float2bfloat16(v.w);
  }
  if (tid < 64) ssh[tid] = s[blockRow + tid];
  bsh[tid] = bias[tid];
  __syncthreads();

  const int wave = tid >> 6, lane = tid & 63;
  const int quad = lane >> 4, c16 = lane & 15;

  float4v acc[4][4];
#pragma unroll
  for (int m = 0; m < 4; ++m)
#pragma unroll
    for (int nn = 0; nn < 4; ++nn)
      acc[m][nn] = (float4v){0.f, 0.f, 0.f, 0.f};

#pragma unroll
  for (int ks = 0; ks < 4; ++ks) {
    short8 a[4], b[4];
#pragma unroll
    for (int m = 0; m < 4; ++m)
      a[m] = *reinterpret_cast<const short8*>(&A[(m * 16 + c16) * 136 + ks * 32 + quad * 8]);
#pragma unroll
    for (int nn = 0; nn < 4; ++nn)
      b[nn] = *reinterpret_cast<const short8*>(
          Wb + ((size_t)(((wave * 4 + nn) * 4 + ks) * 64 + lane)) * 8);
#pragma unroll
    for (int m = 0; m < 4; ++m)
#pragma unroll
      for (int nn = 0; nn < 4; ++nn)
        acc[m][nn] = __builtin_amdgcn_mfma_f32_16x16x32_bf16(a[m], b[nn], acc[m][nn], 0, 0, 0);
  }

  // epilogue: C/D layout col = lane&15, row = quad*4 + reg
#pragma unroll
  for (int m = 0; m < 4; ++m) {
#pragma unroll
    for (int nn = 0; nn < 4; ++nn) {
      const int col = wave * 64 + nn * 16 + c16;
      const float bv = bsh[col];
#pragma unroll
      for (int r = 0; r < 4; ++r) {
        const int row = m * 16 + quad * 4 + r;
        out[(size_t)(blockRow + row) * OUT_CH + col] = ssh[row] * acc[m][nn][r] + bv;
      }
    }
  }
}

// ---------------------------------------------------------------------------
extern "C" void kernel_launch(void* const* d_in, const int* in_sizes, int n_in,
                              void* d_out, int out_size, void* d_ws, size_t ws_size,
                              hipStream_t stream) {
  const float* H    = (const float*)d_in[0];
  const float* U    = (const float*)d_in[1];
  const float* W    = (const float*)d_in[2];
  const float* bias = (const float*)d_in[3];
  float* out = (float*)d_out;

  // ws layout: gram bitmatrix (8 KiB) | s (512 KiB) | Wb (64 KiB)
  char* ws = (char*)d_ws;
  unsigned* gram = (unsigned*)ws;
  float* s = (float*)(ws + 8192);
  __hip_bfloat16* Wb = (__hip_bfloat16*)(ws + 8192 + 524288);

  // node masks live in d_out's first 4 MiB: dead scratch until k_gemm
  // overwrites all of d_out (masks fully consumed by k_scale before that).
  unsigned long long* masks = (unsigned long long*)d_out;

  hipMemsetAsync(gram, 0, E_EDGES * 8 * sizeof(unsigned), stream);
  k_gram<<<dim3(256), dim3(512), 0, stream>>>(H, masks, gram);
  k_convw<<<dim3(64), dim3(64), 0, stream>>>(W, Wb);
  k_scale<<<dim3(512), dim3(256), 0, stream>>>(masks, gram, s);
  k_gemm<<<dim3(N_NODES / 64), dim3(256), 0, stream>>>(U, Wb, s, bias, out);
}

// Round 3
// 299.455 us; speedup vs baseline: 1.0420x; 1.0118x over previous
//
#include <hip/hip_runtime.h>
#include <hip/hip_bf16.h>

typedef __attribute__((ext_vector_type(8))) short short8;
typedef __attribute__((ext_vector_type(4))) float float4v;

#define N_NODES 131072
#define E_EDGES 256
#define IN_CH   128
#define OUT_CH  256

// ---------------------------------------------------------------------------
// k1: per-node 256-bit incidence masks + gram nonzero-pattern bitmatrix.
// gram_nz[e',e] = 1 iff edges e',e share a node = OR_n mask_n ⊗ mask_n.
// Lane L of each wave owns gram rows {L, 64+L, 128+L, 192+L} in 32 VGPRs:
// update per node is pure predicated VALU (no LDS atomics in the loop).
// One-time LDS merge + conditional global atomicOr at the end.
// Block 256 instead converts W fp32 -> bf16 in MFMA B-fragment order:
// Wb[(f*64 + lane)*8 + j] = W[k][col], col=(f>>2)*16+(lane&15),
// k=(f&3)*32+(lane>>4)*8+j  -> 16B/lane contiguous loads in the GEMM.
// ---------------------------------------------------------------------------
__global__ __launch_bounds__(512) void k_gram(const float* __restrict__ H,
                                              const float* __restrict__ W,
                                              unsigned long long* __restrict__ masks,
                                              unsigned* __restrict__ gram,
                                              __hip_bfloat16* __restrict__ Wb) {
  if (blockIdx.x == 256) {  // weight-conversion block
    for (int i = threadIdx.x; i < IN_CH * OUT_CH; i += 512) {
      const int f = i >> 9, lane = (i >> 3) & 63, j = i & 7;
      const int col = (f >> 2) * 16 + (lane & 15);
      const int k = (f & 3) * 32 + (lane >> 4) * 8 + j;
      Wb[i] = __float2bfloat16(W[k * OUT_CH + col]);
    }
    return;
  }

  const int wave = threadIdx.x >> 6;   // 0..7
  const int lane = threadIdx.x & 63;
  const int base = (blockIdx.x * 8 + wave) * 64;  // 64 nodes per wave

  unsigned r[4][8];
#pragma unroll
  for (int g = 0; g < 4; ++g)
#pragma unroll
    for (int j = 0; j < 8; ++j) r[g][j] = 0u;

  for (int it = 0; it < 16; ++it) {    // 4 nodes/iter -> 16 loads in flight
    const int n0 = base + it * 4;
    float v[4][4];
#pragma unroll
    for (int q = 0; q < 4; ++q) {
      const float* row = H + (size_t)(n0 + q) * E_EDGES;
#pragma unroll
      for (int g = 0; g < 4; ++g) v[q][g] = row[lane + g * 64];
    }
#pragma unroll
    for (int q = 0; q < 4; ++q) {
      unsigned long long b0 = __ballot(v[q][0] >= 0.5f);
      unsigned long long b1 = __ballot(v[q][1] >= 0.5f);
      unsigned long long b2 = __ballot(v[q][2] >= 0.5f);
      unsigned long long b3 = __ballot(v[q][3] >= 0.5f);
      if (lane < 4)
        masks[(size_t)(n0 + q) * 4 + lane] =
            (lane == 0) ? b0 : (lane == 1) ? b1 : (lane == 2) ? b2 : b3;
      unsigned w[8] = {(unsigned)b0, (unsigned)(b0 >> 32),
                       (unsigned)b1, (unsigned)(b1 >> 32),
                       (unsigned)b2, (unsigned)(b2 >> 32),
                       (unsigned)b3, (unsigned)(b3 >> 32)};
      const unsigned long long bb[4] = {b0, b1, b2, b3};
#pragma unroll
      for (int g = 0; g < 4; ++g) {
        const unsigned sel = ((unsigned)(bb[g] >> lane) & 1u) ? 0xFFFFFFFFu : 0u;
#pragma unroll
        for (int j = 0; j < 8; ++j) r[g][j] |= w[j] & sel;
      }
    }
  }

  __shared__ unsigned gsh[E_EDGES * 8];
  for (int i = threadIdx.x; i < E_EDGES * 8; i += 512) gsh[i] = 0u;
  __syncthreads();
#pragma unroll
  for (int g = 0; g < 4; ++g)
#pragma unroll
    for (int j = 0; j < 8; ++j)
      if (r[g][j]) atomicOr(&gsh[(g * 64 + lane) * 8 + j], r[g][j]);
  __syncthreads();
  for (int i = threadIdx.x; i < E_EDGES * 8; i += 512) {
    unsigned v = gsh[i];
    if (v) {
      // racy pre-read is safe: OR is monotone, stale read only costs an atomic
      unsigned old = gram[i];
      if ((old | v) != old) atomicOr(&gram[i], v);
    }
  }
}

// ---------------------------------------------------------------------------
// k2: fused scale+GEMM. out[n,c] = s[n]*(U[n,:]@W[:,c]) + bias[c].
// Per block: tile 64 rows x 256 cols, K=128 staged in LDS (bf16, stride 136
// to break ds_read_b128 bank aliasing). Gram bitmatrix (8 KiB) + 64 node
// masks staged to LDS; wave 0 computes s[row] = 1 + rsqrt(dv) right after
// the staging barrier (overlaps other waves' MFMA), epilogue applies it.
// ---------------------------------------------------------------------------
__global__ __launch_bounds__(256) void k_gemm(const float* __restrict__ U,
                                              const __hip_bfloat16* __restrict__ Wb,
                                              const unsigned long long* __restrict__ masks,
                                              const unsigned* __restrict__ gram,
                                              const float* __restrict__ bias,
                                              float* __restrict__ out) {
  __shared__ __hip_bfloat16 A[64 * 136];
  __shared__ unsigned gsh[E_EDGES * 8];
  __shared__ unsigned long long msh[256];
  __shared__ float ssh[64];
  __shared__ float bsh[OUT_CH];

  const int tid = threadIdx.x;
  const int blockRow = blockIdx.x * 64;

  // stage U tile (64 x 128 fp32) -> bf16 LDS, coalesced float4
#pragma unroll
  for (int i = tid; i < 64 * 32; i += 256) {
    const int row = i >> 5, c4 = i & 31;
    float4 v = reinterpret_cast<const float4*>(U + (size_t)(blockRow + row) * IN_CH)[c4];
    __hip_bfloat16* dst = &A[row * 136 + c4 * 4];
    dst[0] = __float2bfloat16(v.x);
    dst[1] = __float2bfloat16(v.y);
    dst[2] = __float2bfloat16(v.z);
    dst[3] = __float2bfloat16(v.w);
  }
  // stage gram (2048 words) + this block's 64 node masks (256 ull)
  {
    uint4* g4 = reinterpret_cast<uint4*>(gsh);
    const uint4* src = reinterpret_cast<const uint4*>(gram);
    g4[tid] = src[tid];
    g4[tid + 256] = src[tid + 256];
    if (tid < 128)
      reinterpret_cast<uint4*>(msh)[tid] =
          reinterpret_cast<const uint4*>(masks + (size_t)blockRow * 4)[tid];
  }
  bsh[tid] = bias[tid];
  __syncthreads();

  // wave 0: per-row scale while other waves start MFMA
  if (tid < 64) {
    const unsigned long long m0 = msh[tid * 4 + 0];
    const unsigned long long m1 = msh[tid * 4 + 1];
    const unsigned long long m2 = msh[tid * 4 + 2];
    const unsigned long long m3 = msh[tid * 4 + 3];
    int dv = __popcll(m0) + __popcll(m1) + __popcll(m2) + __popcll(m3);
    unsigned o0 = 0, o1 = 0, o2 = 0, o3 = 0, o4 = 0, o5 = 0, o6 = 0, o7 = 0;
    auto scan = [&](unsigned long long bits, int g) {
      while (bits) {
        int t = __builtin_ctzll(bits);
        bits &= bits - 1;
        const unsigned* gr = &gsh[((g << 6) + t) * 8];
        o0 |= gr[0]; o1 |= gr[1]; o2 |= gr[2]; o3 |= gr[3];
        o4 |= gr[4]; o5 |= gr[5]; o6 |= gr[6]; o7 |= gr[7];
      }
    };
    scan(m0, 0); scan(m1, 1); scan(m2, 2); scan(m3, 3);
    dv += __popc(o0) + __popc(o1) + __popc(o2) + __popc(o3) +
          __popc(o4) + __popc(o5) + __popc(o6) + __popc(o7);
    float sv = 1.0f;
    if (dv > 0) sv += 1.0f / sqrtf((float)dv);
    ssh[tid] = sv;
  }

  const int wave = tid >> 6, lane = tid & 63;
  const int quad = lane >> 4, c16 = lane & 15;

  float4v acc[4][4];
#pragma unroll
  for (int m = 0; m < 4; ++m)
#pragma unroll
    for (int nn = 0; nn < 4; ++nn)
      acc[m][nn] = (float4v){0.f, 0.f, 0.f, 0.f};

#pragma unroll
  for (int ks = 0; ks < 4; ++ks) {
    short8 a[4], b[4];
#pragma unroll
    for (int m = 0; m < 4; ++m)
      a[m] = *reinterpret_cast<const short8*>(&A[(m * 16 + c16) * 136 + ks * 32 + quad * 8]);
#pragma unroll
    for (int nn = 0; nn < 4; ++nn)
      b[nn] = *reinterpret_cast<const short8*>(
          Wb + ((size_t)(((wave * 4 + nn) * 4 + ks) * 64 + lane)) * 8);
#pragma unroll
    for (int m = 0; m < 4; ++m)
#pragma unroll
      for (int nn = 0; nn < 4; ++nn)
        acc[m][nn] = __builtin_amdgcn_mfma_f32_16x16x32_bf16(a[m], b[nn], acc[m][nn], 0, 0, 0);
  }

  __syncthreads();  // ssh ready for all waves

  // epilogue: C/D layout col = lane&15, row = quad*4 + reg
#pragma unroll
  for (int m = 0; m < 4; ++m) {
#pragma unroll
    for (int nn = 0; nn < 4; ++nn) {
      const int col = wave * 64 + nn * 16 + c16;
      const float bv = bsh[col];
#pragma unroll
      for (int r = 0; r < 4; ++r) {
        const int row = m * 16 + quad * 4 + r;
        out[(size_t)(blockRow + row) * OUT_CH + col] = ssh[row] * acc[m][nn][r] + bv;
      }
    }
  }
}

// ---------------------------------------------------------------------------
extern "C" void kernel_launch(void* const* d_in, const int* in_sizes, int n_in,
                              void* d_out, int out_size, void* d_ws, size_t ws_size,
                              hipStream_t stream) {
  const float* H    = (const float*)d_in[0];
  const float* U    = (const float*)d_in[1];
  const float* W    = (const float*)d_in[2];
  const float* bias = (const float*)d_in[3];
  float* out = (float*)d_out;

  // ws layout: gram bitmatrix (8 KiB) | masks (4 MiB) | Wb (64 KiB)
  char* ws = (char*)d_ws;
  unsigned* gram = (unsigned*)ws;
  unsigned long long* masks = (unsigned long long*)(ws + 8192);
  __hip_bfloat16* Wb = (__hip_bfloat16*)(ws + 8192 + (size_t)N_NODES * 32);

  hipMemsetAsync(gram, 0, E_EDGES * 8 * sizeof(unsigned), stream);
  k_gram<<<dim3(257), dim3(512), 0, stream>>>(H, W, masks, gram, Wb);
  k_gemm<<<dim3(N_NODES / 64), dim3(256), 0, stream>>>(U, Wb, masks, gram, bias, out);
}